// Round 1
// baseline (480.653 us; speedup 1.0000x reference)
//
#include <hip/hip_runtime.h>
#include <stdint.h>

// ---------------------------------------------------------------------------
// NestedSwiGLUMLP: out = (silu(g)*u*mask) @ w2[:, :Hh]^T + b2,  z = x@w1^T + b1
// B=8 S=4096 D=1024 H=2048 Hh=1024 E=4, tokens M=32768
// Strategy: bf16 MFMA with error-compensated (hi+lo) split of x in GEMM1.
// ws layout: a (bf16, 64MB) | w1b (bf16, 4MB) | w2b (bf16, 2MB)  => 73.4 MB
// ---------------------------------------------------------------------------

typedef __attribute__((ext_vector_type(8))) __bf16 bf16x8;
typedef __attribute__((ext_vector_type(8))) unsigned short u16x8;
typedef __attribute__((ext_vector_type(4))) float f32x4;

#define MFMA16(a, b, c) __builtin_amdgcn_mfma_f32_16x16x32_bf16(a, b, c, 0, 0, 0)

static __device__ __forceinline__ unsigned short f2bf(float f) {
  union { float f; uint32_t u; } v; v.f = f;
  uint32_t r = v.u + 0x7FFFu + ((v.u >> 16) & 1u);   // RNE
  return (unsigned short)(r >> 16);
}
static __device__ __forceinline__ float bf2f(unsigned short h) {
  union { uint32_t u; float f; } v; v.u = ((uint32_t)h) << 16;
  return v.f;
}

// async global->LDS, 16B per lane; lds dest = wave-uniform base + lane*16
static __device__ __forceinline__ void gload_lds16(const void* g, void* l) {
  __builtin_amdgcn_global_load_lds(
      (const __attribute__((address_space(1))) void*)g,
      (__attribute__((address_space(3))) void*)l, 16, 0, 0);
}

// ------------------------- weight cast kernels -----------------------------
__global__ void conv_w1_kernel(const float* __restrict__ w1,
                               unsigned short* __restrict__ w1b) {
  int i = blockIdx.x * 256 + threadIdx.x;           // 524288 float4s
  float4 v = ((const float4*)w1)[i];
  ushort4 o; o.x = f2bf(v.x); o.y = f2bf(v.y); o.z = f2bf(v.z); o.w = f2bf(v.w);
  ((ushort4*)w1b)[i] = o;
}

__global__ void conv_w2_kernel(const float* __restrict__ w2,
                               unsigned short* __restrict__ w2b) {
  int i = blockIdx.x * 256 + threadIdx.x;           // 262144 quads
  int d = i >> 8;                                   // row (1024 rows)
  int h4 = (i & 255) * 4;                           // col within first Hh=1024
  float4 v = *(const float4*)(w2 + (size_t)d * 2048 + h4);
  ushort4 o; o.x = f2bf(v.x); o.y = f2bf(v.y); o.z = f2bf(v.z); o.w = f2bf(v.w);
  *(ushort4*)(w2b + (size_t)d * 1024 + h4) = o;
}

// ------------------------- GEMM1 + swiglu epilogue --------------------------
// grid (16, 256): x = Hh tile (64 cols of gate + matching up), y = 128 tokens
__global__ __launch_bounds__(256, 2)
void gemm1_kernel(const float* __restrict__ x, const int* __restrict__ emask,
                  const unsigned short* __restrict__ w1b,
                  const float* __restrict__ b1,
                  unsigned short* __restrict__ a_out) {
  __shared__ __align__(16) char lds[49152];
  char* AHI = lds;            // 128 rows x 128B (bf16 hi), XOR-swizzled
  char* ALO = lds + 16384;    // 128 rows x 128B (bf16 lo)
  char* BS  = lds + 32768;    // gate tile 64x128B @0, up tile 64x128B @8192

  const int tid = threadIdx.x;
  const int lane = tid & 63;
  const int w = tid >> 6;        // wave 0..3
  const int wm = w & 1;          // 64-row half
  const int wn = w >> 1;         // 32-col half
  const int m0 = blockIdx.y * 128;
  const int n0 = blockIdx.x * 64;      // h in [0,1024)

  f32x4 accg[4][2] = {};
  f32x4 accu[4][2] = {};

  const int arow = tid >> 3;     // 0..31 (+32 per iter)
  const int aseg = tid & 7;      // 8-float segment within row

  for (int k0 = 0; k0 < 1024; k0 += 64) {
    // --- B tiles (w1 bf16) via global_load_lds, source pre-swizzled ---
    #pragma unroll
    for (int i = 0; i < 4; ++i) {
      int c = (w * 4 + i) * 64 + lane;        // 16B chunk id in [0,1024)
      int p = c * 16;                         // physical byte in BS
      int tile = p >> 13;                     // 0 = gate, 1 = up
      int r = (p >> 7) & 63;
      int kb16 = ((p >> 4) & 7) ^ (r & 7);    // logical 16B chunk in row
      int h = tile ? (1024 + n0 + r) : (n0 + r);
      const void* gsrc = (const char*)w1b + (((size_t)h * 1024 + k0) * 2) + kb16 * 16;
      gload_lds16(gsrc, BS + (w * 4 + i) * 1024);
    }
    // --- A tile: fp32 -> bf16 hi/lo split, swizzled ds_write_b128 ---
    #pragma unroll
    for (int it = 0; it < 4; ++it) {
      int row = arow + it * 32;
      const float* src = x + (size_t)(m0 + row) * 1024 + k0 + aseg * 8;
      float4 v0 = *(const float4*)(src);
      float4 v1 = *(const float4*)(src + 4);
      float fv[8] = {v0.x, v0.y, v0.z, v0.w, v1.x, v1.y, v1.z, v1.w};
      u16x8 hu, lu;
      #pragma unroll
      for (int j = 0; j < 8; ++j) {
        unsigned short h = f2bf(fv[j]);
        hu[j] = h;
        lu[j] = f2bf(fv[j] - bf2f(h));
      }
      int o = (row * 128 + aseg * 16) ^ ((row & 7) << 4);
      *(u16x8*)(AHI + o) = hu;
      *(u16x8*)(ALO + o) = lu;
    }
    __syncthreads();
    // --- compute ---
    #pragma unroll
    for (int kk = 0; kk < 2; ++kk) {
      const int kbyte = kk * 64 + (lane >> 4) * 16;
      bf16x8 ahi[4], alo[4], bg[2], bu[2];
      #pragma unroll
      for (int m = 0; m < 4; ++m) {
        int r = wm * 64 + m * 16 + (lane & 15);
        int o = (r * 128 + kbyte) ^ ((r & 7) << 4);
        ahi[m] = *(const bf16x8*)(AHI + o);
        alo[m] = *(const bf16x8*)(ALO + o);
      }
      #pragma unroll
      for (int n = 0; n < 2; ++n) {
        int r = wn * 32 + n * 16 + (lane & 15);
        int o = (r * 128 + kbyte) ^ ((r & 7) << 4);
        bg[n] = *(const bf16x8*)(BS + o);
        bu[n] = *(const bf16x8*)(BS + 8192 + o);
      }
      #pragma unroll
      for (int m = 0; m < 4; ++m)
        #pragma unroll
        for (int n = 0; n < 2; ++n) {
          accg[m][n] = MFMA16(ahi[m], bg[n], accg[m][n]);
          accg[m][n] = MFMA16(alo[m], bg[n], accg[m][n]);
          accu[m][n] = MFMA16(ahi[m], bu[n], accu[m][n]);
          accu[m][n] = MFMA16(alo[m], bu[n], accu[m][n]);
        }
    }
    __syncthreads();
  }
  // --- epilogue: a = silu(g + b1g) * (u + b1u) * (col < 128<<expert) ---
  #pragma unroll
  for (int m = 0; m < 4; ++m) {
    int rbase = m0 + wm * 64 + m * 16 + (lane >> 4) * 4;
    int act[4];
    #pragma unroll
    for (int r = 0; r < 4; ++r) act[r] = 128 << emask[rbase + r];
    #pragma unroll
    for (int n = 0; n < 2; ++n) {
      int col = n0 + wn * 32 + n * 16 + (lane & 15);
      float b1g = b1[col], b1u = b1[col + 1024];
      #pragma unroll
      for (int r = 0; r < 4; ++r) {
        float g = accg[m][n][r] + b1g;
        float u = accu[m][n][r] + b1u;
        float s = g / (1.f + __expf(-g));
        float val = (col < act[r]) ? (s * u) : 0.f;
        a_out[(size_t)(rbase + r) * 1024 + col] = f2bf(val);
      }
    }
  }
}

// ------------------------- GEMM2: out = a @ w2b^T + b2 ----------------------
// grid (8, 256): x = 128 output cols (D), y = 128 tokens
__global__ __launch_bounds__(256, 2)
void gemm2_kernel(const unsigned short* __restrict__ a_in,
                  const unsigned short* __restrict__ w2b,
                  const float* __restrict__ b2, float* __restrict__ out) {
  __shared__ __align__(16) char lds[32768];
  char* AS = lds;             // 128 rows x 128B, swizzled
  char* BSS = lds + 16384;    // 128 rows x 128B, swizzled

  const int tid = threadIdx.x;
  const int lane = tid & 63;
  const int w = tid >> 6;
  const int wm = w & 1;
  const int wn = w >> 1;
  const int m0 = blockIdx.y * 128;
  const int n0 = blockIdx.x * 128;

  f32x4 acc[4][4] = {};

  for (int k0 = 0; k0 < 1024; k0 += 64) {
    #pragma unroll
    for (int i = 0; i < 4; ++i) {
      int c = (w * 4 + i) * 64 + lane;        // [0,1024): covers one 16KB tile
      int p = c * 16;
      int r = p >> 7;                         // 0..127
      int kb16 = ((p >> 4) & 7) ^ (r & 7);
      gload_lds16((const char*)a_in + (((size_t)(m0 + r) * 1024 + k0) * 2) + kb16 * 16,
                  AS + (w * 4 + i) * 1024);
      gload_lds16((const char*)w2b + (((size_t)(n0 + r) * 1024 + k0) * 2) + kb16 * 16,
                  BSS + (w * 4 + i) * 1024);
    }
    __syncthreads();
    #pragma unroll
    for (int kk = 0; kk < 2; ++kk) {
      const int kbyte = kk * 64 + (lane >> 4) * 16;
      bf16x8 af[4], bf[4];
      #pragma unroll
      for (int m = 0; m < 4; ++m) {
        int r = wm * 64 + m * 16 + (lane & 15);
        int o = (r * 128 + kbyte) ^ ((r & 7) << 4);
        af[m] = *(const bf16x8*)(AS + o);
      }
      #pragma unroll
      for (int n = 0; n < 4; ++n) {
        int r = wn * 64 + n * 16 + (lane & 15);
        int o = (r * 128 + kbyte) ^ ((r & 7) << 4);
        bf[n] = *(const bf16x8*)(BSS + o);
      }
      #pragma unroll
      for (int m = 0; m < 4; ++m)
        #pragma unroll
        for (int n = 0; n < 4; ++n)
          acc[m][n] = MFMA16(af[m], bf[n], acc[m][n]);
    }
    __syncthreads();
  }
  #pragma unroll
  for (int m = 0; m < 4; ++m) {
    int row = m0 + wm * 64 + m * 16 + (lane >> 4) * 4;
    #pragma unroll
    for (int n = 0; n < 4; ++n) {
      int col = n0 + wn * 64 + n * 16 + (lane & 15);
      float bb = b2[col];
      #pragma unroll
      for (int r = 0; r < 4; ++r)
        out[(size_t)(row + r) * 1024 + col] = acc[m][n][r] + bb;
    }
  }
}

// ---------------------------------------------------------------------------
extern "C" void kernel_launch(void* const* d_in, const int* in_sizes, int n_in,
                              void* d_out, int out_size, void* d_ws, size_t ws_size,
                              hipStream_t stream) {
  const float* x  = (const float*)d_in[0];
  const int* em   = (const int*)d_in[1];
  const float* w1 = (const float*)d_in[2];
  const float* b1 = (const float*)d_in[3];
  const float* w2 = (const float*)d_in[4];
  const float* b2 = (const float*)d_in[5];
  float* out = (float*)d_out;

  char* ws = (char*)d_ws;
  unsigned short* a_ws = (unsigned short*)ws;                   // 67108864 B
  unsigned short* w1b  = (unsigned short*)(ws + 67108864);      //  4194304 B
  unsigned short* w2b  = (unsigned short*)(ws + 71303168);      //  2097152 B
  // total ws need: 73400320 bytes

  conv_w1_kernel<<<2048, 256, 0, stream>>>(w1, w1b);
  conv_w2_kernel<<<1024, 256, 0, stream>>>(w2, w2b);
  gemm1_kernel<<<dim3(16, 256), 256, 0, stream>>>(x, em, w1b, b1, a_ws);
  gemm2_kernel<<<dim3(8, 256), 256, 0, stream>>>(a_ws, w2b, b2, out);
}

// Round 2
// 321.146 us; speedup vs baseline: 1.4967x; 1.4967x over previous
//
#include <hip/hip_runtime.h>
#include <stdint.h>

// ---------------------------------------------------------------------------
// NestedSwiGLUMLP: out = (silu(g)*u*mask) @ w2[:, :Hh]^T + b2,  z = x@w1^T + b1
// B=8 S=4096 D=1024 H=2048 Hh=1024 E=4, tokens M=32768
// R2: single bf16 (no hi/lo split) in GEMM1 — absmax headroom is 3.2x.
//     A-conversion via compiler bf16 casts (v_cvt_pk_bf16_f32).
// ws layout: a (bf16, 64MB) | w1b (bf16, 4MB) | w2b (bf16, 2MB)  => 73.4 MB
// ---------------------------------------------------------------------------

typedef __attribute__((ext_vector_type(8))) __bf16 bf16x8;
typedef __attribute__((ext_vector_type(4))) float f32x4;

#define MFMA16(a, b, c) __builtin_amdgcn_mfma_f32_16x16x32_bf16(a, b, c, 0, 0, 0)

static __device__ __forceinline__ unsigned short f2bf(float f) {
  union { float f; uint32_t u; } v; v.f = f;
  uint32_t r = v.u + 0x7FFFu + ((v.u >> 16) & 1u);   // RNE
  return (unsigned short)(r >> 16);
}

// async global->LDS, 16B per lane; lds dest = wave-uniform base + lane*16
static __device__ __forceinline__ void gload_lds16(const void* g, void* l) {
  __builtin_amdgcn_global_load_lds(
      (const __attribute__((address_space(1))) void*)g,
      (__attribute__((address_space(3))) void*)l, 16, 0, 0);
}

// ------------------------- weight cast kernels -----------------------------
__global__ void conv_w1_kernel(const float* __restrict__ w1,
                               unsigned short* __restrict__ w1b) {
  int i = blockIdx.x * 256 + threadIdx.x;           // 524288 float4s
  float4 v = ((const float4*)w1)[i];
  ushort4 o; o.x = f2bf(v.x); o.y = f2bf(v.y); o.z = f2bf(v.z); o.w = f2bf(v.w);
  ((ushort4*)w1b)[i] = o;
}

__global__ void conv_w2_kernel(const float* __restrict__ w2,
                               unsigned short* __restrict__ w2b) {
  int i = blockIdx.x * 256 + threadIdx.x;           // 262144 quads
  int d = i >> 8;                                   // row (1024 rows)
  int h4 = (i & 255) * 4;                           // col within first Hh=1024
  float4 v = *(const float4*)(w2 + (size_t)d * 2048 + h4);
  ushort4 o; o.x = f2bf(v.x); o.y = f2bf(v.y); o.z = f2bf(v.z); o.w = f2bf(v.w);
  *(ushort4*)(w2b + (size_t)d * 1024 + h4) = o;
}

// ------------------------- GEMM1 + swiglu epilogue --------------------------
// grid (16, 256): x = Hh tile (64 cols of gate + matching up), y = 128 tokens
__global__ __launch_bounds__(256, 2)
void gemm1_kernel(const float* __restrict__ x, const int* __restrict__ emask,
                  const unsigned short* __restrict__ w1b,
                  const float* __restrict__ b1,
                  unsigned short* __restrict__ a_out) {
  __shared__ __align__(16) char lds[32768];
  char* AS = lds;             // 128 rows x 128B (bf16), XOR-swizzled
  char* BS = lds + 16384;     // gate tile 64x128B @0, up tile 64x128B @8192

  const int tid = threadIdx.x;
  const int lane = tid & 63;
  const int w = tid >> 6;        // wave 0..3
  const int wm = w & 1;          // 64-row half
  const int wn = w >> 1;         // 32-col half
  const int m0 = blockIdx.y * 128;
  const int n0 = blockIdx.x * 64;      // h in [0,1024)

  f32x4 accg[4][2] = {};
  f32x4 accu[4][2] = {};

  const int arow = tid >> 3;     // 0..31 (+32 per iter)
  const int aseg = tid & 7;      // 8-float segment within row

  for (int k0 = 0; k0 < 1024; k0 += 64) {
    // --- B tiles (w1 bf16) via global_load_lds, source pre-swizzled ---
    #pragma unroll
    for (int i = 0; i < 4; ++i) {
      int c = (w * 4 + i) * 64 + lane;        // 16B chunk id in [0,1024)
      int p = c * 16;                         // physical byte in BS
      int tile = p >> 13;                     // 0 = gate, 1 = up
      int r = (p >> 7) & 63;
      int kb16 = ((p >> 4) & 7) ^ (r & 7);    // logical 16B chunk in row
      int h = tile ? (1024 + n0 + r) : (n0 + r);
      const void* gsrc = (const char*)w1b + (((size_t)h * 1024 + k0) * 2) + kb16 * 16;
      gload_lds16(gsrc, BS + (w * 4 + i) * 1024);
    }
    // --- A tile: fp32 -> bf16 (compiler cvt_pk), swizzled ds_write_b128 ---
    #pragma unroll
    for (int it = 0; it < 4; ++it) {
      int row = arow + it * 32;
      const float* src = x + (size_t)(m0 + row) * 1024 + k0 + aseg * 8;
      float4 v0 = *(const float4*)(src);
      float4 v1 = *(const float4*)(src + 4);
      float fv[8] = {v0.x, v0.y, v0.z, v0.w, v1.x, v1.y, v1.z, v1.w};
      bf16x8 hv;
      #pragma unroll
      for (int j = 0; j < 8; ++j) hv[j] = (__bf16)fv[j];
      int o = (row * 128 + aseg * 16) ^ ((row & 7) << 4);
      *(bf16x8*)(AS + o) = hv;
    }
    __syncthreads();
    // --- compute ---
    #pragma unroll
    for (int kk = 0; kk < 2; ++kk) {
      const int kbyte = kk * 64 + (lane >> 4) * 16;
      bf16x8 af[4], bg[2], bu[2];
      #pragma unroll
      for (int m = 0; m < 4; ++m) {
        int r = wm * 64 + m * 16 + (lane & 15);
        int o = (r * 128 + kbyte) ^ ((r & 7) << 4);
        af[m] = *(const bf16x8*)(AS + o);
      }
      #pragma unroll
      for (int n = 0; n < 2; ++n) {
        int r = wn * 32 + n * 16 + (lane & 15);
        int o = (r * 128 + kbyte) ^ ((r & 7) << 4);
        bg[n] = *(const bf16x8*)(BS + o);
        bu[n] = *(const bf16x8*)(BS + 8192 + o);
      }
      #pragma unroll
      for (int m = 0; m < 4; ++m)
        #pragma unroll
        for (int n = 0; n < 2; ++n) {
          accg[m][n] = MFMA16(af[m], bg[n], accg[m][n]);
          accu[m][n] = MFMA16(af[m], bu[n], accu[m][n]);
        }
    }
    __syncthreads();
  }
  // --- epilogue: a = silu(g + b1g) * (u + b1u) * (col < 128<<expert) ---
  #pragma unroll
  for (int m = 0; m < 4; ++m) {
    int rbase = m0 + wm * 64 + m * 16 + (lane >> 4) * 4;
    int act[4];
    #pragma unroll
    for (int r = 0; r < 4; ++r) act[r] = 128 << emask[rbase + r];
    #pragma unroll
    for (int n = 0; n < 2; ++n) {
      int col = n0 + wn * 32 + n * 16 + (lane & 15);
      float b1g = b1[col], b1u = b1[col + 1024];
      #pragma unroll
      for (int r = 0; r < 4; ++r) {
        float g = accg[m][n][r] + b1g;
        float u = accu[m][n][r] + b1u;
        float s = g / (1.f + __expf(-g));
        float val = (col < act[r]) ? (s * u) : 0.f;
        a_out[(size_t)(rbase + r) * 1024 + col] = f2bf(val);
      }
    }
  }
}

// ------------------------- GEMM2: out = a @ w2b^T + b2 ----------------------
// grid (8, 256): x = 128 output cols (D), y = 128 tokens
__global__ __launch_bounds__(256, 2)
void gemm2_kernel(const unsigned short* __restrict__ a_in,
                  const unsigned short* __restrict__ w2b,
                  const float* __restrict__ b2, float* __restrict__ out) {
  __shared__ __align__(16) char lds[32768];
  char* AS = lds;             // 128 rows x 128B, swizzled
  char* BSS = lds + 16384;    // 128 rows x 128B, swizzled

  const int tid = threadIdx.x;
  const int lane = tid & 63;
  const int w = tid >> 6;
  const int wm = w & 1;
  const int wn = w >> 1;
  const int m0 = blockIdx.y * 128;
  const int n0 = blockIdx.x * 128;

  f32x4 acc[4][4] = {};

  for (int k0 = 0; k0 < 1024; k0 += 64) {
    #pragma unroll
    for (int i = 0; i < 4; ++i) {
      int c = (w * 4 + i) * 64 + lane;        // [0,1024): covers one 16KB tile
      int p = c * 16;
      int r = p >> 7;                         // 0..127
      int kb16 = ((p >> 4) & 7) ^ (r & 7);
      gload_lds16((const char*)a_in + (((size_t)(m0 + r) * 1024 + k0) * 2) + kb16 * 16,
                  AS + (w * 4 + i) * 1024);
      gload_lds16((const char*)w2b + (((size_t)(n0 + r) * 1024 + k0) * 2) + kb16 * 16,
                  BSS + (w * 4 + i) * 1024);
    }
    __syncthreads();
    #pragma unroll
    for (int kk = 0; kk < 2; ++kk) {
      const int kbyte = kk * 64 + (lane >> 4) * 16;
      bf16x8 af[4], bf[4];
      #pragma unroll
      for (int m = 0; m < 4; ++m) {
        int r = wm * 64 + m * 16 + (lane & 15);
        int o = (r * 128 + kbyte) ^ ((r & 7) << 4);
        af[m] = *(const bf16x8*)(AS + o);
      }
      #pragma unroll
      for (int n = 0; n < 4; ++n) {
        int r = wn * 64 + n * 16 + (lane & 15);
        int o = (r * 128 + kbyte) ^ ((r & 7) << 4);
        bf[n] = *(const bf16x8*)(BSS + o);
      }
      #pragma unroll
      for (int m = 0; m < 4; ++m)
        #pragma unroll
        for (int n = 0; n < 4; ++n)
          acc[m][n] = MFMA16(af[m], bf[n], acc[m][n]);
    }
    __syncthreads();
  }
  #pragma unroll
  for (int m = 0; m < 4; ++m) {
    int row = m0 + wm * 64 + m * 16 + (lane >> 4) * 4;
    #pragma unroll
    for (int n = 0; n < 4; ++n) {
      int col = n0 + wn * 64 + n * 16 + (lane & 15);
      float bb = b2[col];
      #pragma unroll
      for (int r = 0; r < 4; ++r)
        out[(size_t)(row + r) * 1024 + col] = acc[m][n][r] + bb;
    }
  }
}

// ---------------------------------------------------------------------------
extern "C" void kernel_launch(void* const* d_in, const int* in_sizes, int n_in,
                              void* d_out, int out_size, void* d_ws, size_t ws_size,
                              hipStream_t stream) {
  const float* x  = (const float*)d_in[0];
  const int* em   = (const int*)d_in[1];
  const float* w1 = (const float*)d_in[2];
  const float* b1 = (const float*)d_in[3];
  const float* w2 = (const float*)d_in[4];
  const float* b2 = (const float*)d_in[5];
  float* out = (float*)d_out;

  char* ws = (char*)d_ws;
  unsigned short* a_ws = (unsigned short*)ws;                   // 67108864 B
  unsigned short* w1b  = (unsigned short*)(ws + 67108864);      //  4194304 B
  unsigned short* w2b  = (unsigned short*)(ws + 71303168);      //  2097152 B
  // total ws need: 73400320 bytes

  conv_w1_kernel<<<2048, 256, 0, stream>>>(w1, w1b);
  conv_w2_kernel<<<1024, 256, 0, stream>>>(w2, w2b);
  gemm1_kernel<<<dim3(16, 256), 256, 0, stream>>>(x, em, w1b, b1, a_ws);
  gemm2_kernel<<<dim3(8, 256), 256, 0, stream>>>(a_ws, w2b, b2, out);
}

// Round 3
// 248.217 us; speedup vs baseline: 1.9364x; 1.2938x over previous
//
#include <hip/hip_runtime.h>
#include <stdint.h>

// ---------------------------------------------------------------------------
// NestedSwiGLUMLP: out = (silu(g)*u*mask) @ w2[:, :Hh]^T + b2,  z = x@w1^T + b1
// B=8 S=4096 D=1024 H=2048 Hh=1024 E=4, tokens M=32768
// R3: expert-sorted sparsity. Tokens sorted by expert (deterministic ballot-
//     rank sort); gemm1 skips N-tiles >= block max active width (47% avg
//     compute); gemm2 bounds K to block max. x pre-converted to bf16 sorted
//     (xs) so gemm1 becomes the proven pure-bf16 gload_lds structure.
//     Falls back to the R2 path if ws_size < 134.3 MB.
// ---------------------------------------------------------------------------

typedef __attribute__((ext_vector_type(8))) __bf16 bf16x8;
typedef __attribute__((ext_vector_type(4))) float f32x4;

#define MFMA16(a, b, c) __builtin_amdgcn_mfma_f32_16x16x32_bf16(a, b, c, 0, 0, 0)

static __device__ __forceinline__ unsigned short f2bf(float f) {
  union { float f; uint32_t u; } v; v.f = f;
  uint32_t r = v.u + 0x7FFFu + ((v.u >> 16) & 1u);   // RNE
  return (unsigned short)(r >> 16);
}

// async global->LDS, 16B per lane; lds dest = wave-uniform base + lane*16
static __device__ __forceinline__ void gload_lds16(const void* g, void* l) {
  __builtin_amdgcn_global_load_lds(
      (const __attribute__((address_space(1))) void*)g,
      (__attribute__((address_space(3))) void*)l, 16, 0, 0);
}

// ------------------------- weight cast kernels -----------------------------
__global__ void conv_w1_kernel(const float* __restrict__ w1,
                               unsigned short* __restrict__ w1b) {
  int i = blockIdx.x * 256 + threadIdx.x;           // 524288 float4s
  float4 v = ((const float4*)w1)[i];
  ushort4 o; o.x = f2bf(v.x); o.y = f2bf(v.y); o.z = f2bf(v.z); o.w = f2bf(v.w);
  ((ushort4*)w1b)[i] = o;
}

__global__ void conv_w2_kernel(const float* __restrict__ w2,
                               unsigned short* __restrict__ w2b) {
  int i = blockIdx.x * 256 + threadIdx.x;           // 262144 quads
  int d = i >> 8;
  int h4 = (i & 255) * 4;
  float4 v = *(const float4*)(w2 + (size_t)d * 2048 + h4);
  ushort4 o; o.x = f2bf(v.x); o.y = f2bf(v.y); o.z = f2bf(v.z); o.w = f2bf(v.w);
  *(ushort4*)(w2b + (size_t)d * 1024 + h4) = o;
}

// ------------------------- sort kernels (deterministic) ---------------------
__global__ void hist_kernel(const int* __restrict__ emask, int* __restrict__ hist) {
  __shared__ int h[4];
  int tid = threadIdx.x;                 // 128 threads
  if (tid < 4) h[tid] = 0;
  __syncthreads();
  int e = emask[blockIdx.x * 128 + tid];
  atomicAdd(&h[e], 1);
  __syncthreads();
  if (tid < 4) hist[blockIdx.x * 4 + tid] = h[tid];
}

__global__ void scan_kernel(const int* __restrict__ hist, int* __restrict__ off) {
  __shared__ int total[4];
  int tid = threadIdx.x;                 // 64 threads, only 0..3 work
  if (tid < 4) {
    int s = 0;
    for (int b = 0; b < 256; ++b) s += hist[b * 4 + tid];
    total[tid] = s;
  }
  __syncthreads();
  if (tid < 4) {
    int base = 0;
    for (int j = 0; j < tid; ++j) base += total[j];
    int run = base;
    for (int b = 0; b < 256; ++b) {
      off[b * 4 + tid] = run;
      run += hist[b * 4 + tid];
    }
  }
}

__global__ void scatter_kernel(const int* __restrict__ emask,
                               const int* __restrict__ off,
                               int* __restrict__ perm, int* __restrict__ em_sorted) {
  __shared__ int c0[4];
  int tid = threadIdx.x;                 // 128 threads = 2 waves
  int lane = tid & 63, wid = tid >> 6;
  int t = blockIdx.x * 128 + tid;
  int e = emask[t];
  unsigned long long b0 = __ballot(e == 0);
  unsigned long long b1 = __ballot(e == 1);
  unsigned long long b2 = __ballot(e == 2);
  unsigned long long b3 = __ballot(e == 3);
  if (tid == 0) {                        // wave0's counts
    c0[0] = __popcll(b0); c0[1] = __popcll(b1);
    c0[2] = __popcll(b2); c0[3] = __popcll(b3);
  }
  __syncthreads();
  unsigned long long mine = (e == 0) ? b0 : (e == 1) ? b1 : (e == 2) ? b2 : b3;
  int rank = __popcll(mine & ((1ull << lane) - 1ull));
  if (wid) rank += c0[e];
  int pos = off[blockIdx.x * 4 + e] + rank;
  perm[pos] = t;
  em_sorted[pos] = e;
}

// ------------- x -> bf16, gathered into sorted order ------------------------
__global__ void xconv_kernel(const float* __restrict__ x, const int* __restrict__ perm,
                             unsigned short* __restrict__ xs) {
  int gid = blockIdx.x * 256 + threadIdx.x;   // 4,194,304 total
  int s = gid >> 7;                           // sorted row
  int seg = gid & 127;                        // 8-float segment
  int tok = perm[s];
  const float* src = x + (size_t)tok * 1024 + seg * 8;
  float4 v0 = *(const float4*)(src);
  float4 v1 = *(const float4*)(src + 4);
  bf16x8 hv;
  hv[0] = (__bf16)v0.x; hv[1] = (__bf16)v0.y; hv[2] = (__bf16)v0.z; hv[3] = (__bf16)v0.w;
  hv[4] = (__bf16)v1.x; hv[5] = (__bf16)v1.y; hv[6] = (__bf16)v1.z; hv[7] = (__bf16)v1.w;
  *(bf16x8*)(xs + (size_t)s * 1024 + seg * 8) = hv;
}

// ---- block-uniform max expert of sorted rows [m0, m0+128) ------------------
static __device__ __forceinline__ int block_max_e(const int* em_sorted, int m0,
                                                  int tid, int* sred) {
  int v = 0;
  if (tid < 128) v = em_sorted[m0 + tid];
  #pragma unroll
  for (int o = 32; o; o >>= 1) v = max(v, __shfl_xor(v, o));
  if ((tid & 63) == 0) sred[tid >> 6] = v;
  __syncthreads();
  return max(sred[0], sred[1]);
}

// --------- GEMM1 sorted: z tile + swiglu epilogue, N-skip ------------------
// grid (16, 256): x = 64-col tile of gate (+ matching up), y = 128 sorted rows
__global__ __launch_bounds__(256, 2)
void gemm1_sorted_kernel(const unsigned short* __restrict__ xs,
                         const int* __restrict__ em_sorted,
                         const unsigned short* __restrict__ w1b,
                         const float* __restrict__ b1,
                         unsigned short* __restrict__ a_out) {
  __shared__ __align__(16) char lds[32768];
  __shared__ int sred[4];
  char* AS = lds;             // 128 rows x 128B, swizzled
  char* BS = lds + 16384;     // rows 0..63 = gate n0+r, 64..127 = up 1024+n0+r

  const int tid = threadIdx.x;
  const int lane = tid & 63;
  const int w = tid >> 6;
  const int wm = w & 1;
  const int wn = w >> 1;
  const int m0 = blockIdx.y * 128;
  const int n0 = blockIdx.x * 64;

  int maxe = block_max_e(em_sorted, m0, tid, sred);
  if (n0 >= (128 << maxe)) return;      // whole tile inactive for this group

  f32x4 accg[4][2] = {};
  f32x4 accu[4][2] = {};

  for (int k0 = 0; k0 < 1024; k0 += 64) {
    #pragma unroll
    for (int i = 0; i < 4; ++i) {
      int c = (w * 4 + i) * 64 + lane;        // 16B chunk id in [0,1024)
      int p = c * 16;
      int r = p >> 7;                         // 0..127
      int kb16 = ((p >> 4) & 7) ^ (r & 7);
      // A tile from xs (sorted, linear)
      gload_lds16((const char*)xs + (((size_t)(m0 + r) * 1024 + k0) * 2) + kb16 * 16,
                  AS + (w * 4 + i) * 1024);
      // B tile from w1b: gate rows then up rows
      int h = (r < 64) ? (n0 + r) : (1024 + n0 + (r - 64));
      gload_lds16((const char*)w1b + (((size_t)h * 1024 + k0) * 2) + kb16 * 16,
                  BS + (w * 4 + i) * 1024);
    }
    __syncthreads();
    #pragma unroll
    for (int kk = 0; kk < 2; ++kk) {
      const int kbyte = kk * 64 + (lane >> 4) * 16;
      bf16x8 af[4], bg[2], bu[2];
      #pragma unroll
      for (int m = 0; m < 4; ++m) {
        int r = wm * 64 + m * 16 + (lane & 15);
        int o = (r * 128 + kbyte) ^ ((r & 7) << 4);
        af[m] = *(const bf16x8*)(AS + o);
      }
      #pragma unroll
      for (int n = 0; n < 2; ++n) {
        int r = wn * 32 + n * 16 + (lane & 15);
        int o = (r * 128 + kbyte) ^ ((r & 7) << 4);
        bg[n] = *(const bf16x8*)(BS + o);
        bu[n] = *(const bf16x8*)(BS + 8192 + o);
      }
      #pragma unroll
      for (int m = 0; m < 4; ++m)
        #pragma unroll
        for (int n = 0; n < 2; ++n) {
          accg[m][n] = MFMA16(af[m], bg[n], accg[m][n]);
          accu[m][n] = MFMA16(af[m], bu[n], accu[m][n]);
        }
    }
    __syncthreads();
  }
  // epilogue: a = silu(g + b1g) * (u + b1u) * (col < 128<<e)
  #pragma unroll
  for (int m = 0; m < 4; ++m) {
    int rbase = m0 + wm * 64 + m * 16 + (lane >> 4) * 4;
    int act[4];
    #pragma unroll
    for (int r = 0; r < 4; ++r) act[r] = 128 << em_sorted[rbase + r];
    #pragma unroll
    for (int n = 0; n < 2; ++n) {
      int col = n0 + wn * 32 + n * 16 + (lane & 15);
      float b1g = b1[col], b1u = b1[col + 1024];
      #pragma unroll
      for (int r = 0; r < 4; ++r) {
        float g = accg[m][n][r] + b1g;
        float u = accu[m][n][r] + b1u;
        float s = g / (1.f + __expf(-g));
        float val = (col < act[r]) ? (s * u) : 0.f;
        a_out[(size_t)(rbase + r) * 1024 + col] = f2bf(val);
      }
    }
  }
}

// --------- GEMM2 sorted: out = a @ w2b^T + b2, K-bounded, scatter out -------
// grid (8, 256)
__global__ __launch_bounds__(256, 2)
void gemm2_sorted_kernel(const unsigned short* __restrict__ a_in,
                         const int* __restrict__ em_sorted,
                         const int* __restrict__ perm,
                         const unsigned short* __restrict__ w2b,
                         const float* __restrict__ b2, float* __restrict__ out) {
  __shared__ __align__(16) char lds[32768];
  __shared__ int sred[4];
  char* AS = lds;
  char* BSS = lds + 16384;

  const int tid = threadIdx.x;
  const int lane = tid & 63;
  const int w = tid >> 6;
  const int wm = w & 1;
  const int wn = w >> 1;
  const int m0 = blockIdx.y * 128;
  const int n0 = blockIdx.x * 128;

  int maxe = block_max_e(em_sorted, m0, tid, sred);
  const int kmax = 128 << maxe;         // multiple of 64; a[:, kmax:) is 0/unused

  f32x4 acc[4][4] = {};

  for (int k0 = 0; k0 < kmax; k0 += 64) {
    #pragma unroll
    for (int i = 0; i < 4; ++i) {
      int c = (w * 4 + i) * 64 + lane;
      int p = c * 16;
      int r = p >> 7;
      int kb16 = ((p >> 4) & 7) ^ (r & 7);
      gload_lds16((const char*)a_in + (((size_t)(m0 + r) * 1024 + k0) * 2) + kb16 * 16,
                  AS + (w * 4 + i) * 1024);
      gload_lds16((const char*)w2b + (((size_t)(n0 + r) * 1024 + k0) * 2) + kb16 * 16,
                  BSS + (w * 4 + i) * 1024);
    }
    __syncthreads();
    #pragma unroll
    for (int kk = 0; kk < 2; ++kk) {
      const int kbyte = kk * 64 + (lane >> 4) * 16;
      bf16x8 af[4], bf[4];
      #pragma unroll
      for (int m = 0; m < 4; ++m) {
        int r = wm * 64 + m * 16 + (lane & 15);
        int o = (r * 128 + kbyte) ^ ((r & 7) << 4);
        af[m] = *(const bf16x8*)(AS + o);
      }
      #pragma unroll
      for (int n = 0; n < 4; ++n) {
        int r = wn * 64 + n * 16 + (lane & 15);
        int o = (r * 128 + kbyte) ^ ((r & 7) << 4);
        bf[n] = *(const bf16x8*)(BSS + o);
      }
      #pragma unroll
      for (int m = 0; m < 4; ++m)
        #pragma unroll
        for (int n = 0; n < 4; ++n)
          acc[m][n] = MFMA16(af[m], bf[n], acc[m][n]);
    }
    __syncthreads();
  }
  #pragma unroll
  for (int m = 0; m < 4; ++m) {
    int rbase = m0 + wm * 64 + m * 16 + (lane >> 4) * 4;
    #pragma unroll
    for (int n = 0; n < 4; ++n) {
      int col = n0 + wn * 64 + n * 16 + (lane & 15);
      float bb = b2[col];
      #pragma unroll
      for (int r = 0; r < 4; ++r) {
        int tok = perm[rbase + r];
        out[(size_t)tok * 1024 + col] = acc[m][n][r] + bb;
      }
    }
  }
}

// ======================= R2 fallback kernels (unsorted) =====================
__global__ __launch_bounds__(256, 2)
void gemm1_plain_kernel(const float* __restrict__ x, const int* __restrict__ emask,
                        const unsigned short* __restrict__ w1b,
                        const float* __restrict__ b1,
                        unsigned short* __restrict__ a_out) {
  __shared__ __align__(16) char lds[32768];
  char* AS = lds;
  char* BS = lds + 16384;

  const int tid = threadIdx.x;
  const int lane = tid & 63;
  const int w = tid >> 6;
  const int wm = w & 1;
  const int wn = w >> 1;
  const int m0 = blockIdx.y * 128;
  const int n0 = blockIdx.x * 64;

  f32x4 accg[4][2] = {};
  f32x4 accu[4][2] = {};

  const int arow = tid >> 3;
  const int aseg = tid & 7;

  for (int k0 = 0; k0 < 1024; k0 += 64) {
    #pragma unroll
    for (int i = 0; i < 4; ++i) {
      int c = (w * 4 + i) * 64 + lane;
      int p = c * 16;
      int tile = p >> 13;
      int r = (p >> 7) & 63;
      int kb16 = ((p >> 4) & 7) ^ (r & 7);
      int h = tile ? (1024 + n0 + r) : (n0 + r);
      gload_lds16((const char*)w1b + (((size_t)h * 1024 + k0) * 2) + kb16 * 16,
                  BS + (w * 4 + i) * 1024);
    }
    #pragma unroll
    for (int it = 0; it < 4; ++it) {
      int row = arow + it * 32;
      const float* src = x + (size_t)(m0 + row) * 1024 + k0 + aseg * 8;
      float4 v0 = *(const float4*)(src);
      float4 v1 = *(const float4*)(src + 4);
      float fv[8] = {v0.x, v0.y, v0.z, v0.w, v1.x, v1.y, v1.z, v1.w};
      bf16x8 hv;
      #pragma unroll
      for (int j = 0; j < 8; ++j) hv[j] = (__bf16)fv[j];
      int o = (row * 128 + aseg * 16) ^ ((row & 7) << 4);
      *(bf16x8*)(AS + o) = hv;
    }
    __syncthreads();
    #pragma unroll
    for (int kk = 0; kk < 2; ++kk) {
      const int kbyte = kk * 64 + (lane >> 4) * 16;
      bf16x8 af[4], bg[2], bu[2];
      #pragma unroll
      for (int m = 0; m < 4; ++m) {
        int r = wm * 64 + m * 16 + (lane & 15);
        int o = (r * 128 + kbyte) ^ ((r & 7) << 4);
        af[m] = *(const bf16x8*)(AS + o);
      }
      #pragma unroll
      for (int n = 0; n < 2; ++n) {
        int r = wn * 32 + n * 16 + (lane & 15);
        int o = (r * 128 + kbyte) ^ ((r & 7) << 4);
        bg[n] = *(const bf16x8*)(BS + o);
        bu[n] = *(const bf16x8*)(BS + 8192 + o);
      }
      #pragma unroll
      for (int m = 0; m < 4; ++m)
        #pragma unroll
        for (int n = 0; n < 2; ++n) {
          accg[m][n] = MFMA16(af[m], bg[n], accg[m][n]);
          accu[m][n] = MFMA16(af[m], bu[n], accu[m][n]);
        }
    }
    __syncthreads();
  }
  #pragma unroll
  for (int m = 0; m < 4; ++m) {
    int rbase = m0 + wm * 64 + m * 16 + (lane >> 4) * 4;
    int act[4];
    #pragma unroll
    for (int r = 0; r < 4; ++r) act[r] = 128 << emask[rbase + r];
    #pragma unroll
    for (int n = 0; n < 2; ++n) {
      int col = n0 + wn * 32 + n * 16 + (lane & 15);
      float b1g = b1[col], b1u = b1[col + 1024];
      #pragma unroll
      for (int r = 0; r < 4; ++r) {
        float g = accg[m][n][r] + b1g;
        float u = accu[m][n][r] + b1u;
        float s = g / (1.f + __expf(-g));
        float val = (col < act[r]) ? (s * u) : 0.f;
        a_out[(size_t)(rbase + r) * 1024 + col] = f2bf(val);
      }
    }
  }
}

__global__ __launch_bounds__(256, 2)
void gemm2_plain_kernel(const unsigned short* __restrict__ a_in,
                        const unsigned short* __restrict__ w2b,
                        const float* __restrict__ b2, float* __restrict__ out) {
  __shared__ __align__(16) char lds[32768];
  char* AS = lds;
  char* BSS = lds + 16384;

  const int tid = threadIdx.x;
  const int lane = tid & 63;
  const int w = tid >> 6;
  const int wm = w & 1;
  const int wn = w >> 1;
  const int m0 = blockIdx.y * 128;
  const int n0 = blockIdx.x * 128;

  f32x4 acc[4][4] = {};

  for (int k0 = 0; k0 < 1024; k0 += 64) {
    #pragma unroll
    for (int i = 0; i < 4; ++i) {
      int c = (w * 4 + i) * 64 + lane;
      int p = c * 16;
      int r = p >> 7;
      int kb16 = ((p >> 4) & 7) ^ (r & 7);
      gload_lds16((const char*)a_in + (((size_t)(m0 + r) * 1024 + k0) * 2) + kb16 * 16,
                  AS + (w * 4 + i) * 1024);
      gload_lds16((const char*)w2b + (((size_t)(n0 + r) * 1024 + k0) * 2) + kb16 * 16,
                  BSS + (w * 4 + i) * 1024);
    }
    __syncthreads();
    #pragma unroll
    for (int kk = 0; kk < 2; ++kk) {
      const int kbyte = kk * 64 + (lane >> 4) * 16;
      bf16x8 af[4], bf[4];
      #pragma unroll
      for (int m = 0; m < 4; ++m) {
        int r = wm * 64 + m * 16 + (lane & 15);
        int o = (r * 128 + kbyte) ^ ((r & 7) << 4);
        af[m] = *(const bf16x8*)(AS + o);
      }
      #pragma unroll
      for (int n = 0; n < 4; ++n) {
        int r = wn * 64 + n * 16 + (lane & 15);
        int o = (r * 128 + kbyte) ^ ((r & 7) << 4);
        bf[n] = *(const bf16x8*)(BSS + o);
      }
      #pragma unroll
      for (int m = 0; m < 4; ++m)
        #pragma unroll
        for (int n = 0; n < 4; ++n)
          acc[m][n] = MFMA16(af[m], bf[n], acc[m][n]);
    }
    __syncthreads();
  }
  #pragma unroll
  for (int m = 0; m < 4; ++m) {
    int row = m0 + wm * 64 + m * 16 + (lane >> 4) * 4;
    #pragma unroll
    for (int n = 0; n < 4; ++n) {
      int col = n0 + wn * 64 + n * 16 + (lane & 15);
      float bb = b2[col];
      #pragma unroll
      for (int r = 0; r < 4; ++r)
        out[(size_t)(row + r) * 1024 + col] = acc[m][n][r] + bb;
    }
  }
}

// ---------------------------------------------------------------------------
extern "C" void kernel_launch(void* const* d_in, const int* in_sizes, int n_in,
                              void* d_out, int out_size, void* d_ws, size_t ws_size,
                              hipStream_t stream) {
  const float* x  = (const float*)d_in[0];
  const int* em   = (const int*)d_in[1];
  const float* w1 = (const float*)d_in[2];
  const float* b1 = (const float*)d_in[3];
  const float* w2 = (const float*)d_in[4];
  const float* b2 = (const float*)d_in[5];
  float* out = (float*)d_out;

  char* ws = (char*)d_ws;
  unsigned short* a_ws = (unsigned short*)ws;                   // 67108864 B
  unsigned short* w1b  = (unsigned short*)(ws + 67108864);      //  4194304 B
  unsigned short* w2b  = (unsigned short*)(ws + 71303168);      //  2097152 B
  unsigned short* xs   = (unsigned short*)(ws + 73400320);      // 67108864 B
  int* perm      = (int*)(ws + 140509184);                      //   131072 B
  int* em_sorted = (int*)(ws + 140640256);                      //   131072 B
  int* hist      = (int*)(ws + 140771328);                      //     4096 B
  int* off       = (int*)(ws + 140775424);                      //     4096 B
  const size_t NEED = 140779520;

  conv_w1_kernel<<<2048, 256, 0, stream>>>(w1, w1b);
  conv_w2_kernel<<<1024, 256, 0, stream>>>(w2, w2b);

  if (ws_size >= NEED) {
    hist_kernel<<<256, 128, 0, stream>>>(em, hist);
    scan_kernel<<<1, 64, 0, stream>>>(hist, off);
    scatter_kernel<<<256, 128, 0, stream>>>(em, off, perm, em_sorted);
    xconv_kernel<<<16384, 256, 0, stream>>>(x, perm, xs);
    gemm1_sorted_kernel<<<dim3(16, 256), 256, 0, stream>>>(xs, em_sorted, w1b, b1, a_ws);
    gemm2_sorted_kernel<<<dim3(8, 256), 256, 0, stream>>>(a_ws, em_sorted, perm, w2b, b2, out);
  } else {
    gemm1_plain_kernel<<<dim3(16, 256), 256, 0, stream>>>(x, em, w1b, b1, a_ws);
    gemm2_plain_kernel<<<dim3(8, 256), 256, 0, stream>>>(a_ws, w2b, b2, out);
  }
}